// Round 8
// baseline (124.226 us; speedup 1.0000x reference)
//
#include <hip/hip_runtime.h>
#include <hip/hip_fp16.h>
#include <math.h>

#define N_HEADS 8
#define N_LEVELS 4
#define N_POINTS 4
#define LQ 5440
#define LV 5440
#define BATCH_ 4
#define M_TOT (BATCH_ * LQ)   // 21760

typedef __bf16 bf16x8 __attribute__((ext_vector_type(8)));
typedef float f32x4 __attribute__((ext_vector_type(4)));
typedef unsigned int uint_t;

__device__ __forceinline__ unsigned short rne_bf16(float x) {
  uint_t u = __float_as_uint(x);
  uint_t r = u + 0x7fffu + ((u >> 16) & 1u);
  return (unsigned short)(r >> 16);
}
__device__ __forceinline__ float bf16_to_f(unsigned short h) {
  return __uint_as_float(((uint_t)h) << 16);
}
__device__ __forceinline__ uint_t f2h2(float a, float b) {   // pack 2 f32 -> half2 (RNE)
  const unsigned short ua = __half_as_ushort(__float2half(a));
  const unsigned short ub = __half_as_ushort(__float2half(b));
  return (uint_t)ua | ((uint_t)ub << 16);
}
__device__ __forceinline__ float h_lo(uint_t u) {
  return __half2float(__ushort_as_half((unsigned short)(u & 0xffffu)));
}
__device__ __forceinline__ float h_hi(uint_t u) {
  return __half2float(__ushort_as_half((unsigned short)(u >> 16)));
}

// ---------------- input conversion: query -> Q3 (hi|lo), input_flatten -> IFh ----------------
// Also zeroes the 128B guard after valb (block 0) so the sampler's one-past-end
// x-pair reads always see finite bf16 data.
__global__ __launch_bounds__(256) void conv_inputs(
    const float* __restrict__ q, const float* __restrict__ iff,
    unsigned short* __restrict__ Q3, unsigned short* __restrict__ IFh,
    unsigned short* __restrict__ guardp)
{
  if (blockIdx.x == 0 && threadIdx.x < 64) guardp[threadIdx.x] = 0;
  const int t = blockIdx.x * 256 + threadIdx.x;   // 0 .. M*64
  const int r = t >> 6;
  const int c = (t & 63) * 4;
  const float4 qa = *(const float4*)(q + (size_t)r * 256 + c);
  ushort4 h, l;
  {
    const float v[4] = {qa.x, qa.y, qa.z, qa.w};
    unsigned short hh[4], ll[4];
#pragma unroll
    for (int i = 0; i < 4; ++i) {
      hh[i] = rne_bf16(v[i]);
      ll[i] = rne_bf16(v[i] - bf16_to_f(hh[i]));
    }
    h = make_ushort4(hh[0], hh[1], hh[2], hh[3]);
    l = make_ushort4(ll[0], ll[1], ll[2], ll[3]);
  }
  *(ushort4*)(Q3 + (size_t)r * 512 + c) = h;
  *(ushort4*)(Q3 + (size_t)r * 512 + 256 + c) = l;
  const float4 fa = *(const float4*)(iff + (size_t)r * 256 + c);
  *(ushort4*)(IFh + (size_t)r * 256 + c) =
      make_ushort4(rne_bf16(fa.x), rne_bf16(fa.y), rne_bf16(fa.z), rne_bf16(fa.w));
}

// ---------------- weight conversion (transpose + bf16) ----------------
// mode 1 (2-term split): W[n][0..255]=hi, [256..511]=hi  (pairs with A=[hi|lo])
// mode 0: Wt[n][0..255]=hi
// Wcat: rows 0..255 = w_off, rows 256..383 = w_attn (both mode 1)
__global__ __launch_bounds__(256) void conv_weights(
    const float* __restrict__ w_off, const float* __restrict__ w_out,
    const float* __restrict__ w_val, const float* __restrict__ w_attn,
    unsigned short* __restrict__ Wcat, unsigned short* __restrict__ Wo2,
    unsigned short* __restrict__ Wvt)
{
  __shared__ float tbuf[64][65];
  const int tid = threadIdx.x;
  const int k0 = blockIdx.x * 64;
  const int yy = blockIdx.y;
  const float* src; unsigned short* dst; int N; int mode; int ntile; int roff = 0;
  if (yy < 4)       { src = w_off;  dst = Wcat; N = 256; mode = 1; ntile = yy; }
  else if (yy < 8)  { src = w_out;  dst = Wo2;  N = 256; mode = 1; ntile = yy - 4; }
  else if (yy < 12) { src = w_val;  dst = Wvt;  N = 256; mode = 0; ntile = yy - 8; }
  else              { src = w_attn; dst = Wcat; N = 128; mode = 1; ntile = yy - 12; roff = 256; }
  const int n0 = ntile * 64;
#pragma unroll
  for (int i = 0; i < 16; ++i) {
    const int r = (tid >> 6) + i * 4;
    const int c = tid & 63;
    tbuf[r][c] = src[(size_t)(k0 + r) * N + n0 + c];
  }
  __syncthreads();
#pragma unroll
  for (int i = 0; i < 16; ++i) {
    const int n = (tid >> 6) + i * 4;
    const int kk = tid & 63;
    const float v = tbuf[kk][n];
    const unsigned short h = rne_bf16(v);
    if (mode) {
      const size_t rowb = (size_t)(roff + n0 + n) * 512;
      dst[rowb + k0 + kk] = h;
      dst[rowb + 256 + k0 + kk] = h;
    } else {
      dst[(size_t)(n0 + n) * 256 + k0 + kk] = h;
    }
  }
}

// ---------------- bf16 MFMA GEMM, m97 structure ----------------
// MODE: 0 = f32 out; 1 = bf16 out;
// 2 = mixed (col<256 -> f32 C1 ldc 256; col>=256 -> bf16 C2 ldc 128);
// 3 = bf16 head-major value layout: C1[((b*8 + col/32)*LV + pos)*32 + col%32], row = b*LV+pos
template<int KSTEPS, int MODE>
__global__ __launch_bounds__(256) void gemm_mfma(
    const unsigned short* __restrict__ A, int lda,
    const unsigned short* __restrict__ Bt,   // [N][KSTEPS*64]
    const float* __restrict__ bias, const float* __restrict__ bias2,
    void* __restrict__ C1, int ldc, void* __restrict__ C2)
{
  constexpr int LDB = KSTEPS * 64;
  __shared__ unsigned short As[128 * 64];
  __shared__ unsigned short Bs[128 * 64];
  const int tid = threadIdx.x;
  const int w = tid >> 6, lane = tid & 63;
  const int wm = w >> 1, wn = w & 1;
  const int lr = lane & 15, lk = lane >> 4;
  const int m0 = blockIdx.y * 128, n0 = blockIdx.x * 128;

  f32x4 acc[4][4] = {};

  for (int t = 0; t < KSTEPS; ++t) {
    const int ka = t * 64;
#pragma unroll
    for (int i = 0; i < 4; ++i) {
      const int rbase = i * 32 + w * 8;
      const int row = rbase + (lane >> 3);
      const int slot = lane & 7;
      const int gs = slot ^ (row & 7);                 // inverse-swizzle the SOURCE (rule 21)
      const unsigned short* gp = A + (size_t)(m0 + row) * lda + ka + gs * 8;
      __builtin_amdgcn_global_load_lds(
          (const __attribute__((address_space(1))) uint_t*)gp,
          (__attribute__((address_space(3))) uint_t*)(As + rbase * 64), 16, 0, 0);
    }
#pragma unroll
    for (int i = 0; i < 4; ++i) {
      const int rbase = i * 32 + w * 8;
      const int row = rbase + (lane >> 3);
      const int slot = lane & 7;
      const int gs = slot ^ (row & 7);
      const unsigned short* gp = Bt + (size_t)(n0 + row) * LDB + ka + gs * 8;
      __builtin_amdgcn_global_load_lds(
          (const __attribute__((address_space(1))) uint_t*)gp,
          (__attribute__((address_space(3))) uint_t*)(Bs + rbase * 64), 16, 0, 0);
    }
    asm volatile("s_waitcnt vmcnt(0)" ::: "memory");
    __syncthreads();
#pragma unroll
    for (int kk = 0; kk < 2; ++kk) {
      bf16x8 af[4], bfv[4];
#pragma unroll
      for (int m = 0; m < 4; ++m) {
        const int row = wm * 64 + m * 16 + lr;
        const int so = (kk * 4 + lk) ^ (row & 7);      // swizzled read
        af[m] = *(const bf16x8*)((const char*)As + row * 128 + so * 16);
      }
#pragma unroll
      for (int n = 0; n < 4; ++n) {
        const int row = wn * 64 + n * 16 + lr;
        const int so = (kk * 4 + lk) ^ (row & 7);
        bfv[n] = *(const bf16x8*)((const char*)Bs + row * 128 + so * 16);
      }
#pragma unroll
      for (int m = 0; m < 4; ++m)
#pragma unroll
        for (int n = 0; n < 4; ++n)
          acc[m][n] = __builtin_amdgcn_mfma_f32_16x16x32_bf16(af[m], bfv[n], acc[m][n], 0, 0, 0);
    }
    __syncthreads();
  }
#pragma unroll
  for (int n = 0; n < 4; ++n) {
    const int col = n0 + wn * 64 + n * 16 + lr;
    const float bv = (MODE == 2 && col >= 256) ? bias2[col - 256] : bias[col];
#pragma unroll
    for (int m = 0; m < 4; ++m) {
      const int rbase = m0 + wm * 64 + m * 16 + lk * 4;
#pragma unroll
      for (int j = 0; j < 4; ++j) {
        const float v = acc[m][n][j] + bv;
        const int row = rbase + j;
        if (MODE == 0) {
          ((float*)C1)[(size_t)row * ldc + col] = v;
        } else if (MODE == 1) {
          ((unsigned short*)C1)[(size_t)row * ldc + col] = rne_bf16(v);
        } else if (MODE == 2) {
          if (col < 256) ((float*)C1)[(size_t)row * 256 + col] = v;
          else           ((unsigned short*)C2)[(size_t)row * 128 + (col - 256)] = rne_bf16(v);
        } else {
          const uint_t bb = (uint_t)row / (uint_t)LV;            // magic-mul const div
          const uint_t pos = (uint_t)row - bb * (uint_t)LV;
          const uint_t hh = (uint_t)col >> 5, dd = (uint_t)col & 31u;
          ((unsigned short*)C1)[(((size_t)(bb * 8u + hh)) * LV + pos) * 32 + dd] = rne_bf16(v);
        }
      }
    }
  }
}

// ---------------- sampler v8: two-phase, head-major value, x-pair coalesced, SAFE indices ----------------
// value layout: [B*8 heads][LV][32ch] bf16; x-pair (x0,x0+1) is 128 B contiguous.
// Quad lane dg reads bytes [dg*32,+32) of the pair block at the 2 y-rows -> 2 requests/point.
// Index safety: y rows clamped to [0,H-1] (weights already masked); x kept RAW down to -1
// (required for pair alignment of a valid x1 when x0=-1), clamped to 0 when both x invalid.
// => indices in [-1, H*W-1]; reads span [valb-64B, valb_end+128B): IFh tail (finite bf16)
// below, zeroed guard above. No Inf/NaN can enter a 0-weight fma.
__global__ __launch_bounds__(256) void msda_sample_v8(
    const float* __restrict__ off_buf,            // [M,256]
    const unsigned short* __restrict__ logit_buf, // [M,128] bf16
    const unsigned short* __restrict__ value,     // [B*8][LV][32] bf16
    const float* __restrict__ ref_pts,            // [B,LQ,4,2]
    const int*  __restrict__ sshapes, const int* __restrict__ lstart,
    unsigned short* __restrict__ samp3)           // [M,512]
{
  __shared__ uint_t wlds[64 * 68];                // 17,408 B
  const int tid = threadIdx.x;
  const int q0 = blockIdx.x * 8;
  const int b  = blockIdx.x / (LQ / 8);
  const int q  = tid >> 5;
  const int qg = q0 + q;

  // ---------- phase 1: lane = (q, h, l) ----------
  {
    const int h  = (tid >> 2) & 7;
    const int l  = tid & 3;
    const int Hl = sshapes[2 * l], Wl = sshapes[2 * l + 1];
    const float rx = ref_pts[(size_t)qg * 8 + l * 2 + 0];
    const float ry = ref_pts[(size_t)qg * 8 + l * 2 + 1];
    const float fx = rx * (float)Wl - 0.5f;
    const float fy = ry * (float)Hl - 0.5f;

    const float* ob = off_buf + (size_t)qg * 256 + h * 32 + l * 8;
    const float4 o0 = *(const float4*)(ob);
    const float4 o1 = *(const float4*)(ob + 4);
    const float offv[8] = {o0.x, o0.y, o0.z, o0.w, o1.x, o1.y, o1.z, o1.w};

    const uint2 lgu = *(const uint2*)(logit_buf + (size_t)qg * 128 + h * 16 + l * 4);
    float lg[4];
    lg[0] = __uint_as_float(lgu.x << 16);
    lg[1] = __uint_as_float(lgu.x & 0xffff0000u);
    lg[2] = __uint_as_float(lgu.y << 16);
    lg[3] = __uint_as_float(lgu.y & 0xffff0000u);

    // cooperative softmax over the 16 logits of (q,h) (4 lanes x 4)
    float mx = fmaxf(fmaxf(lg[0], lg[1]), fmaxf(lg[2], lg[3]));
    mx = fmaxf(mx, __shfl_xor(mx, 1));
    mx = fmaxf(mx, __shfl_xor(mx, 2));
    float ex[4]; float ssum = 0.f;
#pragma unroll
    for (int p = 0; p < 4; ++p) { ex[p] = __expf(lg[p] - mx); ssum += ex[p]; }
    ssum += __shfl_xor(ssum, 1);
    ssum += __shfl_xor(ssum, 2);
    const float inv = 1.f / ssum;

    uint_t* wrow = wlds + (size_t)(q * 8 + h) * 68;

#pragma unroll
    for (int p = 0; p < 4; ++p) {
      const float x = fx + offv[p * 2 + 0];
      const float y = fy + offv[p * 2 + 1];
      const float aw = ex[p] * inv;
      const float xf = floorf(x), yf = floorf(y);
      const int x0i = (int)xf, y0i = (int)yf;
      const float wx1 = x - xf, wy1 = y - yf;
      const float wx0 = 1.f - wx1, wy0 = 1.f - wy1;
      const int x1i = x0i + 1, y1i = y0i + 1;
      const bool vx0 = (uint_t)x0i < (uint_t)Wl, vx1 = (uint_t)x1i < (uint_t)Wl;
      const bool vy0 = (uint_t)y0i < (uint_t)Hl, vy1 = (uint_t)y1i < (uint_t)Hl;
      const float awy0 = aw * wy0, awy1 = aw * wy1;
      const float w00 = (vy0 && vx0) ? awy0 * wx0 : 0.f;
      const float w01 = (vy0 && vx1) ? awy0 * wx1 : 0.f;
      const float w10 = (vy1 && vx0) ? awy1 * wx0 : 0.f;
      const float w11 = (vy1 && vx1) ? awy1 * wx1 : 0.f;
      // SAFE indices: y clamped (weights masked); x raw down to -1 for pair alignment,
      // 0 when both x-sides invalid (all weights 0).
      const int yc0 = min(max(y0i, 0), Hl - 1);
      const int yc1 = min(max(y1i, 0), Hl - 1);
      const int xr  = (vx0 || vx1) ? max(x0i, -1) : 0;
      const int i00 = yc0 * Wl + xr;       // in [-1, H*W-1]
      const int i10 = yc1 * Wl + xr;
      uint4 pk;
      pk.x = f2h2(w00, w01);
      pk.y = f2h2(w10, w11);
      pk.z = ((uint_t)i00 & 0xffffu) | (((uint_t)i10 & 0xffffu) << 16);
      pk.w = 0u;
      *(uint4*)(wrow + (l * 4 + p) * 4) = pk;
    }
  }
  __syncthreads();

  // ---------- phase 2: lane = (q, h, dg) ----------
  const int h  = (tid >> 2) & 7;
  const int dg = tid & 3;
  const int xs = dg >> 1;                       // 0: x0 side, 1: x1 side
  const uint_t* wrow = wlds + (size_t)(q * 8 + h) * 68;
  const int stl[4] = {lstart[0], lstart[1], lstart[2], lstart[3]};   // static idx after unroll
  const char* vhb = (const char*)value + (size_t)((uint_t)(b * 8 + h) * (uint_t)(LV * 64)) + (uint_t)dg * 32u;
  float acc[16] = {};

#define ACCUM8P(AP, U4, WV) {                                                      \
    const uint_t uu0 = (U4).x, uu1 = (U4).y, uu2 = (U4).z, uu3 = (U4).w;           \
    (AP)[0] = fmaf((WV), __uint_as_float(uu0 << 16),         (AP)[0]);             \
    (AP)[1] = fmaf((WV), __uint_as_float(uu0 & 0xffff0000u), (AP)[1]);             \
    (AP)[2] = fmaf((WV), __uint_as_float(uu1 << 16),         (AP)[2]);             \
    (AP)[3] = fmaf((WV), __uint_as_float(uu1 & 0xffff0000u), (AP)[3]);             \
    (AP)[4] = fmaf((WV), __uint_as_float(uu2 << 16),         (AP)[4]);             \
    (AP)[5] = fmaf((WV), __uint_as_float(uu2 & 0xffff0000u), (AP)[5]);             \
    (AP)[6] = fmaf((WV), __uint_as_float(uu3 << 16),         (AP)[6]);             \
    (AP)[7] = fmaf((WV), __uint_as_float(uu3 & 0xffff0000u), (AP)[7]); }

#pragma unroll
  for (int pt = 0; pt < 16; ++pt) {
    const uint4 pk = *(const uint4*)(wrow + pt * 4);
    const float wA = xs ? h_hi(pk.x) : h_lo(pk.x);   // y0 row, my x-side
    const float wB = xs ? h_hi(pk.y) : h_lo(pk.y);   // y1 row, my x-side
    const int i0 = (int)(short)(pk.z & 0xffffu);
    const int i1 = (int)(short)(pk.z >> 16);
    const char* lb = vhb + (ptrdiff_t)stl[pt >> 2] * 64;
    const char* p0 = lb + (ptrdiff_t)i0 * 64;
    const char* p1 = lb + (ptrdiff_t)i1 * 64;
    const uint4 ga0 = *(const uint4*)(p0);
    const uint4 ga1 = *(const uint4*)(p0 + 16);
    const uint4 gb0 = *(const uint4*)(p1);
    const uint4 gb1 = *(const uint4*)(p1 + 16);
    ACCUM8P(acc + 0, ga0, wA);
    ACCUM8P(acc + 8, ga1, wA);
    ACCUM8P(acc + 0, gb0, wB);
    ACCUM8P(acc + 8, gb1, wB);
  }

  // combine x0-side and x1-side partials (lanes dg and dg^2 hold same channels)
#pragma unroll
  for (int c = 0; c < 16; ++c) acc[c] += __shfl_xor(acc[c], 2);

  // lane dg writes channels (dg&1)*16 + xs*8 .. +8
  float o8[8];
#pragma unroll
  for (int i = 0; i < 8; ++i) o8[i] = xs ? acc[8 + i] : acc[i];
  unsigned short h8[8], l8[8];
#pragma unroll
  for (int i = 0; i < 8; ++i) {
    h8[i] = rne_bf16(o8[i]);
    l8[i] = rne_bf16(o8[i] - bf16_to_f(h8[i]));
  }
  const int cb = (dg & 1) * 16 + xs * 8;
  unsigned short* op = samp3 + (size_t)qg * 512 + h * 32 + cb;
  *(ushort4*)(op)       = make_ushort4(h8[0], h8[1], h8[2], h8[3]);
  *(ushort4*)(op + 4)   = make_ushort4(h8[4], h8[5], h8[6], h8[7]);
  *(ushort4*)(op + 256) = make_ushort4(l8[0], l8[1], l8[2], l8[3]);
  *(ushort4*)(op + 260) = make_ushort4(l8[4], l8[5], l8[6], l8[7]);
}

extern "C" void kernel_launch(void* const* d_in, const int* in_sizes, int n_in,
                              void* d_out, int out_size, void* d_ws, size_t ws_size,
                              hipStream_t stream) {
  const float* query         = (const float*)d_in[0];
  const float* ref_pts       = (const float*)d_in[1];
  const float* input_flatten = (const float*)d_in[2];
  const int*   sshapes       = (const int*)d_in[3];
  const int*   lstart        = (const int*)d_in[4];
  const float* w_val  = (const float*)d_in[5];
  const float* b_val  = (const float*)d_in[6];
  const float* w_off  = (const float*)d_in[7];
  const float* b_off  = (const float*)d_in[8];
  const float* w_attn = (const float*)d_in[9];
  const float* b_attn = (const float*)d_in[10];
  const float* w_out  = (const float*)d_in[11];
  const float* b_out  = (const float*)d_in[12];
  float* out = (float*)d_out;

  char* ws = (char*)d_ws;
  unsigned short* Q3     = (unsigned short*)(ws);                 // 22,282,240 B (reused as samp3)
  unsigned short* IFh    = (unsigned short*)(ws + 22282240);      // 11,141,120
  unsigned short* valb   = (unsigned short*)(ws + 33423360);      // 11,141,120  [B*8][LV][32]
  unsigned short* guardp = (unsigned short*)(ws + 44564480);      //        128  zero guard
  float*          offb   = (float*)(ws + 44564608);               // 22,282,240
  unsigned short* logitb = (unsigned short*)(ws + 66846848);      //  5,570,560
  unsigned short* Wcat   = (unsigned short*)(ws + 72417408);      //    393,216  [384][512]
  unsigned short* Wo2    = (unsigned short*)(ws + 72810624);      //    262,144  [256][512]
  unsigned short* Wvt    = (unsigned short*)(ws + 73072768);      //    131,072  [256][256]
  unsigned short* samp3  = Q3;  // Q3 dead after the fused off/logit GEMM

  dim3 blk(256);
  conv_inputs<<<dim3(M_TOT / 4), blk, 0, stream>>>(query, input_flatten, Q3, IFh, guardp);
  conv_weights<<<dim3(4, 14), blk, 0, stream>>>(w_off, w_out, w_val, w_attn, Wcat, Wo2, Wvt);
  // value = IFh @ w_val (plain bf16), head-major bf16 out
  gemm_mfma<4, 3><<<dim3(2, M_TOT / 128), blk, 0, stream>>>(
      IFh, 256, Wvt, b_val, nullptr, (void*)valb, 256, nullptr);
  // fused: [off | logits] = [Q_hi|Q_lo] @ Wcat^T, K=512, mixed epilogue
  gemm_mfma<8, 2><<<dim3(3, M_TOT / 128), blk, 0, stream>>>(
      Q3, 512, Wcat, b_off, b_attn, (void*)offb, 256, (void*)logitb);
  msda_sample_v8<<<dim3(M_TOT / 8), blk, 0, stream>>>(
      offb, logitb, valb, ref_pts, sshapes, lstart, samp3);
  // out = [samp_hi|samp_lo] @ [Wo_hi|Wo_hi], K=512, out f32
  gemm_mfma<8, 0><<<dim3(2, M_TOT / 128), blk, 0, stream>>>(
      samp3, 512, Wo2, b_out, nullptr, (void*)out, 256, nullptr);
}

// Round 9
// 119.512 us; speedup vs baseline: 1.0394x; 1.0394x over previous
//
#include <hip/hip_runtime.h>
#include <hip/hip_fp16.h>
#include <math.h>

#define N_HEADS 8
#define N_LEVELS 4
#define N_POINTS 4
#define LQ 5440
#define LV 5440
#define BATCH_ 4
#define M_TOT (BATCH_ * LQ)   // 21760

typedef __bf16 bf16x8 __attribute__((ext_vector_type(8)));
typedef float f32x4 __attribute__((ext_vector_type(4)));
typedef unsigned int uint_t;

__device__ __forceinline__ unsigned short rne_bf16(float x) {
  uint_t u = __float_as_uint(x);
  uint_t r = u + 0x7fffu + ((u >> 16) & 1u);
  return (unsigned short)(r >> 16);
}
__device__ __forceinline__ float bf16_to_f(unsigned short h) {
  return __uint_as_float(((uint_t)h) << 16);
}
__device__ __forceinline__ uint_t f2h2(float a, float b) {   // pack 2 f32 -> half2 (RNE)
  const unsigned short ua = __half_as_ushort(__float2half(a));
  const unsigned short ub = __half_as_ushort(__float2half(b));
  return (uint_t)ua | ((uint_t)ub << 16);
}
__device__ __forceinline__ float h_lo(uint_t u) {
  return __half2float(__ushort_as_half((unsigned short)(u & 0xffffu)));
}
__device__ __forceinline__ float h_hi(uint_t u) {
  return __half2float(__ushort_as_half((unsigned short)(u >> 16)));
}
// HW packed f32->bf16 (RNE), 2 elems/instr; no builtin on gfx950 -> inline asm
__device__ __forceinline__ uint_t cvt_pk_bf16(float a, float b) {
  uint_t r;
  asm("v_cvt_pk_bf16_f32 %0, %1, %2" : "=v"(r) : "v"(a), "v"(b));
  return r;
}

// ---------------- weight conversion (transpose + bf16) ----------------
// mode 1 (2-term split): W[n][0..255]=hi, [256..511]=hi  (pairs with A=[hi|lo])
// mode 0: Wt[n][0..255]=hi
// Wcat: rows 0..255 = w_off, rows 256..383 = w_attn (both mode 1)
__global__ __launch_bounds__(256) void conv_weights(
    const float* __restrict__ w_off, const float* __restrict__ w_out,
    const float* __restrict__ w_val, const float* __restrict__ w_attn,
    unsigned short* __restrict__ Wcat, unsigned short* __restrict__ Wo2,
    unsigned short* __restrict__ Wvt)
{
  __shared__ float tbuf[64][65];
  const int tid = threadIdx.x;
  const int k0 = blockIdx.x * 64;
  const int yy = blockIdx.y;
  const float* src; unsigned short* dst; int N; int mode; int ntile; int roff = 0;
  if (yy < 4)       { src = w_off;  dst = Wcat; N = 256; mode = 1; ntile = yy; }
  else if (yy < 8)  { src = w_out;  dst = Wo2;  N = 256; mode = 1; ntile = yy - 4; }
  else if (yy < 12) { src = w_val;  dst = Wvt;  N = 256; mode = 0; ntile = yy - 8; }
  else              { src = w_attn; dst = Wcat; N = 128; mode = 1; ntile = yy - 12; roff = 256; }
  const int n0 = ntile * 64;
#pragma unroll
  for (int i = 0; i < 16; ++i) {
    const int r = (tid >> 6) + i * 4;
    const int c = tid & 63;
    tbuf[r][c] = src[(size_t)(k0 + r) * N + n0 + c];
  }
  __syncthreads();
#pragma unroll
  for (int i = 0; i < 16; ++i) {
    const int n = (tid >> 6) + i * 4;
    const int kk = tid & 63;
    const float v = tbuf[kk][n];
    const unsigned short h = rne_bf16(v);
    if (mode) {
      const size_t rowb = (size_t)(roff + n0 + n) * 512;
      dst[rowb + k0 + kk] = h;
      dst[rowb + 256 + k0 + kk] = h;
    } else {
      dst[(size_t)(n0 + n) * 256 + k0 + kk] = h;
    }
  }
}

// ---------------- bf16 MFMA GEMM, m97 structure, fused A conversion ----------------
// MODE: 0 = f32 out; 1 = bf16 out; 2 = mixed (col<256 -> f32 C1; col>=256 -> bf16 C2 ldc 128)
// ASRC: 0 = A bf16 (global_load_lds); 1 = A f32 -> bf16 hi (reg-staged cvt_pk);
//       2 = A f32 -> [hi|lo] over K=512 (t<4: hi of col (t&3)*64.., t>=4: lo of same cols)
template<int KSTEPS, int MODE, int ASRC>
__global__ __launch_bounds__(256) void gemm_mfma(
    const void* __restrict__ Avoid, int lda,
    const unsigned short* __restrict__ Bt,   // [N][KSTEPS*64]
    const float* __restrict__ bias, const float* __restrict__ bias2,
    void* __restrict__ C1, int ldc, void* __restrict__ C2)
{
  constexpr int LDB = KSTEPS * 64;
  __shared__ unsigned short As[128 * 64];
  __shared__ unsigned short Bs[128 * 64];
  const int tid = threadIdx.x;
  const int w = tid >> 6, lane = tid & 63;
  const int wm = w >> 1, wn = w & 1;
  const int lr = lane & 15, lk = lane >> 4;
  const int m0 = blockIdx.y * 128, n0 = blockIdx.x * 128;

  f32x4 acc[4][4] = {};

  for (int t = 0; t < KSTEPS; ++t) {
    const int ka = t * 64;
    // B staging first (async global_load_lds overlaps A's cvt work)
#pragma unroll
    for (int i = 0; i < 4; ++i) {
      const int rbase = i * 32 + w * 8;
      const int row = rbase + (lane >> 3);
      const int slot = lane & 7;
      const int gs = slot ^ (row & 7);
      const unsigned short* gp = Bt + (size_t)(n0 + row) * LDB + ka + gs * 8;
      __builtin_amdgcn_global_load_lds(
          (const __attribute__((address_space(1))) uint_t*)gp,
          (__attribute__((address_space(3))) uint_t*)(Bs + rbase * 64), 16, 0, 0);
    }
    if constexpr (ASRC == 0) {
      const unsigned short* Abf = (const unsigned short*)Avoid;
#pragma unroll
      for (int i = 0; i < 4; ++i) {
        const int rbase = i * 32 + w * 8;
        const int row = rbase + (lane >> 3);
        const int slot = lane & 7;
        const int gs = slot ^ (row & 7);                 // inverse-swizzle the SOURCE (rule 21)
        const unsigned short* gp = Abf + (size_t)(m0 + row) * lda + ka + gs * 8;
        __builtin_amdgcn_global_load_lds(
            (const __attribute__((address_space(1))) uint_t*)gp,
            (__attribute__((address_space(3))) uint_t*)(As + rbase * 64), 16, 0, 0);
      }
    } else {
      const float* Af = (const float*)Avoid;
      const int acol = (ASRC == 2 ? (t & 3) : t) * 64;
      const bool lohalf = (ASRC == 2) && (t >= 4);
#pragma unroll
      for (int i = 0; i < 4; ++i) {
        const int rbase = i * 32 + w * 8;
        const int row = rbase + (lane >> 3);
        const int slot = lane & 7;
        const int gs = slot ^ (row & 7);
        const float* gp = Af + (size_t)(m0 + row) * lda + acol + gs * 8;
        const float4 a0 = *(const float4*)gp;
        const float4 a1 = *(const float4*)(gp + 4);
        uint_t q0 = cvt_pk_bf16(a0.x, a0.y);
        uint_t q1 = cvt_pk_bf16(a0.z, a0.w);
        uint_t q2 = cvt_pk_bf16(a1.x, a1.y);
        uint_t q3 = cvt_pk_bf16(a1.z, a1.w);
        if (lohalf) {
          // lo = v - hi(v), hi from the SAME cvt_pk -> hi+lo == v exactly
          const float l0 = a0.x - __uint_as_float(q0 << 16);
          const float l1 = a0.y - __uint_as_float(q0 & 0xffff0000u);
          const float l2 = a0.z - __uint_as_float(q1 << 16);
          const float l3 = a0.w - __uint_as_float(q1 & 0xffff0000u);
          const float l4 = a1.x - __uint_as_float(q2 << 16);
          const float l5 = a1.y - __uint_as_float(q2 & 0xffff0000u);
          const float l6 = a1.z - __uint_as_float(q3 << 16);
          const float l7 = a1.w - __uint_as_float(q3 & 0xffff0000u);
          q0 = cvt_pk_bf16(l0, l1);
          q1 = cvt_pk_bf16(l2, l3);
          q2 = cvt_pk_bf16(l4, l5);
          q3 = cvt_pk_bf16(l6, l7);
        }
        *(uint4*)&As[(size_t)row * 64 + slot * 8] = make_uint4(q0, q1, q2, q3);
      }
    }
    asm volatile("s_waitcnt vmcnt(0)" ::: "memory");
    __syncthreads();
#pragma unroll
    for (int kk = 0; kk < 2; ++kk) {
      bf16x8 af[4], bfv[4];
#pragma unroll
      for (int m = 0; m < 4; ++m) {
        const int row = wm * 64 + m * 16 + lr;
        const int so = (kk * 4 + lk) ^ (row & 7);      // swizzled read
        af[m] = *(const bf16x8*)((const char*)As + row * 128 + so * 16);
      }
#pragma unroll
      for (int n = 0; n < 4; ++n) {
        const int row = wn * 64 + n * 16 + lr;
        const int so = (kk * 4 + lk) ^ (row & 7);
        bfv[n] = *(const bf16x8*)((const char*)Bs + row * 128 + so * 16);
      }
#pragma unroll
      for (int m = 0; m < 4; ++m)
#pragma unroll
        for (int n = 0; n < 4; ++n)
          acc[m][n] = __builtin_amdgcn_mfma_f32_16x16x32_bf16(af[m], bfv[n], acc[m][n], 0, 0, 0);
    }
    __syncthreads();
  }
#pragma unroll
  for (int n = 0; n < 4; ++n) {
    const int col = n0 + wn * 64 + n * 16 + lr;
    const float bv = (MODE == 2 && col >= 256) ? bias2[col - 256] : bias[col];
#pragma unroll
    for (int m = 0; m < 4; ++m) {
      const int rbase = m0 + wm * 64 + m * 16 + lk * 4;
#pragma unroll
      for (int j = 0; j < 4; ++j) {
        const float v = acc[m][n][j] + bv;
        const int row = rbase + j;
        if (MODE == 0) {
          ((float*)C1)[(size_t)row * ldc + col] = v;
        } else if (MODE == 1) {
          ((unsigned short*)C1)[(size_t)row * ldc + col] = rne_bf16(v);
        } else {
          if (col < 256) ((float*)C1)[(size_t)row * 256 + col] = v;
          else           ((unsigned short*)C2)[(size_t)row * 128 + (col - 256)] = rne_bf16(v);
        }
      }
    }
  }
}

// ---------------- sampler v9: v6 structure (two-phase, packed 16B/point, fully clamped)
// + __launch_bounds__(256,8) to force VGPR<=64 (occupancy step at 64, m69).
__global__ __launch_bounds__(256, 8) void msda_sample_v9(
    const float* __restrict__ off_buf,            // [M,256]
    const unsigned short* __restrict__ logit_buf, // [M,128] bf16
    const unsigned short* __restrict__ value,     // [B,LV,256] bf16
    const float* __restrict__ ref_pts,            // [B,LQ,4,2]
    const int*  __restrict__ sshapes, const int* __restrict__ lstart,
    unsigned short* __restrict__ samp3)           // [M,512]
{
  __shared__ uint_t wlds[64 * 68];                // 17,408 B
  const int tid = threadIdx.x;
  const int q0 = blockIdx.x * 8;
  const int b  = blockIdx.x / (LQ / 8);
  const int q  = tid >> 5;
  const int qg = q0 + q;

  // ---------- phase 1: lane = (q, h, l) ----------
  {
    const int h  = (tid >> 2) & 7;
    const int l  = tid & 3;
    const int Hl = sshapes[2 * l], Wl = sshapes[2 * l + 1];
    const int st = lstart[l];
    const float rx = ref_pts[(size_t)qg * 8 + l * 2 + 0];
    const float ry = ref_pts[(size_t)qg * 8 + l * 2 + 1];
    const float fx = rx * (float)Wl - 0.5f;
    const float fy = ry * (float)Hl - 0.5f;

    const float* ob = off_buf + (size_t)qg * 256 + h * 32 + l * 8;
    const float4 o0 = *(const float4*)(ob);
    const float4 o1 = *(const float4*)(ob + 4);
    const float offv[8] = {o0.x, o0.y, o0.z, o0.w, o1.x, o1.y, o1.z, o1.w};

    const uint2 lgu = *(const uint2*)(logit_buf + (size_t)qg * 128 + h * 16 + l * 4);
    float lg[4];
    lg[0] = __uint_as_float(lgu.x << 16);
    lg[1] = __uint_as_float(lgu.x & 0xffff0000u);
    lg[2] = __uint_as_float(lgu.y << 16);
    lg[3] = __uint_as_float(lgu.y & 0xffff0000u);

    // cooperative softmax over the 16 logits of (q,h) (4 lanes x 4)
    float mx = fmaxf(fmaxf(lg[0], lg[1]), fmaxf(lg[2], lg[3]));
    mx = fmaxf(mx, __shfl_xor(mx, 1));
    mx = fmaxf(mx, __shfl_xor(mx, 2));
    float ex[4]; float ssum = 0.f;
#pragma unroll
    for (int p = 0; p < 4; ++p) { ex[p] = __expf(lg[p] - mx); ssum += ex[p]; }
    ssum += __shfl_xor(ssum, 1);
    ssum += __shfl_xor(ssum, 2);
    const float inv = 1.f / ssum;

    const uint_t base_idx = (uint_t)b * LV + (uint_t)st;   // absolute element-row base
    uint_t* wrow = wlds + (size_t)(q * 8 + h) * 68;

#pragma unroll
    for (int p = 0; p < 4; ++p) {
      const float x = fx + offv[p * 2 + 0];
      const float y = fy + offv[p * 2 + 1];
      const float aw = ex[p] * inv;
      const float xf = floorf(x), yf = floorf(y);
      const int x0i = (int)xf, y0i = (int)yf;
      const float wx1 = x - xf, wy1 = y - yf;
      const float wx0 = 1.f - wx1, wy0 = 1.f - wy1;
      const int x1i = x0i + 1, y1i = y0i + 1;
      const bool vx0 = (uint_t)x0i < (uint_t)Wl, vx1 = (uint_t)x1i < (uint_t)Wl;
      const bool vy0 = (uint_t)y0i < (uint_t)Hl, vy1 = (uint_t)y1i < (uint_t)Hl;
      const int xc0 = min(max(x0i, 0), Wl - 1), xc1 = min(max(x1i, 0), Wl - 1);
      const int yc0 = min(max(y0i, 0), Hl - 1), yc1 = min(max(y1i, 0), Hl - 1);
      const float awy0 = aw * wy0, awy1 = aw * wy1;
      const float w00 = (vy0 && vx0) ? awy0 * wx0 : 0.f;
      const float w01 = (vy0 && vx1) ? awy0 * wx1 : 0.f;
      const float w10 = (vy1 && vx0) ? awy1 * wx0 : 0.f;
      const float w11 = (vy1 && vx1) ? awy1 * wx1 : 0.f;
      const uint_t r0 = base_idx + (uint_t)(yc0 * Wl), r1 = base_idx + (uint_t)(yc1 * Wl);
      uint4 pk;
      pk.x = f2h2(w00, w01);
      pk.y = f2h2(w10, w11);
      pk.z = (r0 + (uint_t)xc0) | ((r0 + (uint_t)xc1) << 16);
      pk.w = (r1 + (uint_t)xc0) | ((r1 + (uint_t)xc1) << 16);
      *(uint4*)(wrow + (l * 4 + p) * 4) = pk;
    }
  }
  __syncthreads();

  // ---------- phase 2: lane = (q, h, dg) ----------
  const int h  = (tid >> 2) & 7;
  const int dg = tid & 3;
  const uint_t* wrow = wlds + (size_t)(q * 8 + h) * 68;
  const char* vbyte = (const char*)value + (uint_t)h * 64u + (uint_t)dg * 16u;
  float acc[8] = {};

#define ACCUM8V(U4, WV) {                                                          \
    const uint_t uu0 = (U4).x, uu1 = (U4).y, uu2 = (U4).z, uu3 = (U4).w;           \
    acc[0] = fmaf((WV), __uint_as_float(uu0 << 16),         acc[0]);               \
    acc[1] = fmaf((WV), __uint_as_float(uu0 & 0xffff0000u), acc[1]);               \
    acc[2] = fmaf((WV), __uint_as_float(uu1 << 16),         acc[2]);               \
    acc[3] = fmaf((WV), __uint_as_float(uu1 & 0xffff0000u), acc[3]);               \
    acc[4] = fmaf((WV), __uint_as_float(uu2 << 16),         acc[4]);               \
    acc[5] = fmaf((WV), __uint_as_float(uu2 & 0xffff0000u), acc[5]);               \
    acc[6] = fmaf((WV), __uint_as_float(uu3 << 16),         acc[6]);               \
    acc[7] = fmaf((WV), __uint_as_float(uu3 & 0xffff0000u), acc[7]); }

#pragma unroll
  for (int pt = 0; pt < 16; ++pt) {
    const uint4 pk = *(const uint4*)(wrow + pt * 4);
    const float w0 = h_lo(pk.x), w1 = h_hi(pk.x);
    const float w2 = h_lo(pk.y), w3 = h_hi(pk.y);
    const uint_t i0 = pk.z & 0xffffu, i1 = pk.z >> 16;
    const uint_t i2 = pk.w & 0xffffu, i3 = pk.w >> 16;
    { const uint4 g = *(const uint4*)(vbyte + (size_t)i0 * 512u); ACCUM8V(g, w0); }
    { const uint4 g = *(const uint4*)(vbyte + (size_t)i1 * 512u); ACCUM8V(g, w1); }
    { const uint4 g = *(const uint4*)(vbyte + (size_t)i2 * 512u); ACCUM8V(g, w2); }
    { const uint4 g = *(const uint4*)(vbyte + (size_t)i3 * 512u); ACCUM8V(g, w3); }
  }

  unsigned short h8[8], l8[8];
#pragma unroll
  for (int i = 0; i < 8; ++i) {
    h8[i] = rne_bf16(acc[i]);
    l8[i] = rne_bf16(acc[i] - bf16_to_f(h8[i]));
  }
  unsigned short* op = samp3 + (size_t)qg * 512 + h * 32 + dg * 8;
  *(ushort4*)(op)       = make_ushort4(h8[0], h8[1], h8[2], h8[3]);
  *(ushort4*)(op + 4)   = make_ushort4(h8[4], h8[5], h8[6], h8[7]);
  *(ushort4*)(op + 256) = make_ushort4(l8[0], l8[1], l8[2], l8[3]);
  *(ushort4*)(op + 260) = make_ushort4(l8[4], l8[5], l8[6], l8[7]);
}

extern "C" void kernel_launch(void* const* d_in, const int* in_sizes, int n_in,
                              void* d_out, int out_size, void* d_ws, size_t ws_size,
                              hipStream_t stream) {
  const float* query         = (const float*)d_in[0];
  const float* ref_pts       = (const float*)d_in[1];
  const float* input_flatten = (const float*)d_in[2];
  const int*   sshapes       = (const int*)d_in[3];
  const int*   lstart        = (const int*)d_in[4];
  const float* w_val  = (const float*)d_in[5];
  const float* b_val  = (const float*)d_in[6];
  const float* w_off  = (const float*)d_in[7];
  const float* b_off  = (const float*)d_in[8];
  const float* w_attn = (const float*)d_in[9];
  const float* b_attn = (const float*)d_in[10];
  const float* w_out  = (const float*)d_in[11];
  const float* b_out  = (const float*)d_in[12];
  float* out = (float*)d_out;

  char* ws = (char*)d_ws;
  unsigned short* valb   = (unsigned short*)(ws);                 // 11,141,120  [B,LV,256] bf16
  unsigned short* samp3  = (unsigned short*)(ws + 11141120);      // 22,282,240  [M,512] hi|lo
  float*          offb   = (float*)(ws + 33423360);               // 22,282,240  [M,256] f32
  unsigned short* logitb = (unsigned short*)(ws + 55705600);      //  5,570,560  [M,128] bf16
  unsigned short* Wcat   = (unsigned short*)(ws + 61276160);      //    393,216  [384][512]
  unsigned short* Wo2    = (unsigned short*)(ws + 61669376);      //    262,144  [256][512]
  unsigned short* Wvt    = (unsigned short*)(ws + 61931520);      //    131,072  [256][256]

  dim3 blk(256);
  conv_weights<<<dim3(4, 14), blk, 0, stream>>>(w_off, w_out, w_val, w_attn, Wcat, Wo2, Wvt);
  // value = bf16(input_flatten) @ Wvt^T, A converted in-kernel (hi only), out bf16
  gemm_mfma<4, 1, 1><<<dim3(2, M_TOT / 128), blk, 0, stream>>>(
      (const void*)input_flatten, 256, Wvt, b_val, nullptr, (void*)valb, 256, nullptr);
  // fused: [off | logits] = [hi(Q)|lo(Q)] @ Wcat^T, K=512, A converted in-kernel
  gemm_mfma<8, 2, 2><<<dim3(3, M_TOT / 128), blk, 0, stream>>>(
      (const void*)query, 256, Wcat, b_off, b_attn, (void*)offb, 256, (void*)logitb);
  msda_sample_v9<<<dim3(M_TOT / 8), blk, 0, stream>>>(
      offb, logitb, valb, ref_pts, sshapes, lstart, samp3);
  // out = [samp_hi|samp_lo] @ Wo2^T, K=512, A bf16 via global_load_lds
  gemm_mfma<8, 0, 0><<<dim3(2, M_TOT / 128), blk, 0, stream>>>(
      (const void*)samp3, 512, Wo2, b_out, nullptr, (void*)out, 256, nullptr);
}

// Round 10
// 115.193 us; speedup vs baseline: 1.0784x; 1.0375x over previous
//
#include <hip/hip_runtime.h>
#include <hip/hip_fp16.h>
#include <math.h>

#define N_HEADS 8
#define N_LEVELS 4
#define N_POINTS 4
#define LQ 5440
#define LV 5440
#define BATCH_ 4
#define M_TOT (BATCH_ * LQ)   // 21760

typedef __bf16 bf16x8 __attribute__((ext_vector_type(8)));
typedef float f32x4 __attribute__((ext_vector_type(4)));
typedef unsigned int uint_t;

__device__ __forceinline__ unsigned short rne_bf16(float x) {
  uint_t u = __float_as_uint(x);
  uint_t r = u + 0x7fffu + ((u >> 16) & 1u);
  return (unsigned short)(r >> 16);
}
__device__ __forceinline__ float bf16_to_f(unsigned short h) {
  return __uint_as_float(((uint_t)h) << 16);
}
__device__ __forceinline__ uint_t f2h2(float a, float b) {   // pack 2 f32 -> half2 (RNE)
  const unsigned short ua = __half_as_ushort(__float2half(a));
  const unsigned short ub = __half_as_ushort(__float2half(b));
  return (uint_t)ua | ((uint_t)ub << 16);
}
__device__ __forceinline__ float h_lo(uint_t u) {
  return __half2float(__ushort_as_half((unsigned short)(u & 0xffffu)));
}
__device__ __forceinline__ float h_hi(uint_t u) {
  return __half2float(__ushort_as_half((unsigned short)(u >> 16)));
}
// HW packed f32->bf16 (RNE): D.lo = bf16(S0), D.hi = bf16(S1)
__device__ __forceinline__ uint_t cvt_pk_bf16(float a, float b) {
  uint_t r;
  asm("v_cvt_pk_bf16_f32 %0, %1, %2" : "=v"(r) : "v"(a), "v"(b));
  return r;
}

// ---------------- input conversion: query -> Q3 (hi|lo), input_flatten -> IFh ----------------
__global__ __launch_bounds__(256) void conv_inputs(
    const float* __restrict__ q, const float* __restrict__ iff,
    unsigned short* __restrict__ Q3, unsigned short* __restrict__ IFh)
{
  const int t = blockIdx.x * 256 + threadIdx.x;   // 0 .. M*64
  const int r = t >> 6;
  const int c = (t & 63) * 4;
  const float4 qa = *(const float4*)(q + (size_t)r * 256 + c);
  ushort4 h, l;
  {
    const float v[4] = {qa.x, qa.y, qa.z, qa.w};
    unsigned short hh[4], ll[4];
#pragma unroll
    for (int i = 0; i < 4; ++i) {
      hh[i] = rne_bf16(v[i]);
      ll[i] = rne_bf16(v[i] - bf16_to_f(hh[i]));
    }
    h = make_ushort4(hh[0], hh[1], hh[2], hh[3]);
    l = make_ushort4(ll[0], ll[1], ll[2], ll[3]);
  }
  *(ushort4*)(Q3 + (size_t)r * 512 + c) = h;
  *(ushort4*)(Q3 + (size_t)r * 512 + 256 + c) = l;
  const float4 fa = *(const float4*)(iff + (size_t)r * 256 + c);
  *(ushort4*)(IFh + (size_t)r * 256 + c) =
      make_ushort4(rne_bf16(fa.x), rne_bf16(fa.y), rne_bf16(fa.z), rne_bf16(fa.w));
}

// ---------------- weight conversion (transpose + bf16) ----------------
// mode 1 (2-term split): W[n][0..255]=hi, [256..511]=hi  (pairs with A=[hi|lo])
// mode 0: Wt[n][0..255]=hi
// Wcat: rows 0..255 = w_off, rows 256..383 = w_attn (both mode 1)
__global__ __launch_bounds__(256) void conv_weights(
    const float* __restrict__ w_off, const float* __restrict__ w_out,
    const float* __restrict__ w_val, const float* __restrict__ w_attn,
    unsigned short* __restrict__ Wcat, unsigned short* __restrict__ Wo2,
    unsigned short* __restrict__ Wvt)
{
  __shared__ float tbuf[64][65];
  const int tid = threadIdx.x;
  const int k0 = blockIdx.x * 64;
  const int yy = blockIdx.y;
  const float* src; unsigned short* dst; int N; int mode; int ntile; int roff = 0;
  if (yy < 4)       { src = w_off;  dst = Wcat; N = 256; mode = 1; ntile = yy; }
  else if (yy < 8)  { src = w_out;  dst = Wo2;  N = 256; mode = 1; ntile = yy - 4; }
  else if (yy < 12) { src = w_val;  dst = Wvt;  N = 256; mode = 0; ntile = yy - 8; }
  else              { src = w_attn; dst = Wcat; N = 128; mode = 1; ntile = yy - 12; roff = 256; }
  const int n0 = ntile * 64;
#pragma unroll
  for (int i = 0; i < 16; ++i) {
    const int r = (tid >> 6) + i * 4;
    const int c = tid & 63;
    tbuf[r][c] = src[(size_t)(k0 + r) * N + n0 + c];
  }
  __syncthreads();
#pragma unroll
  for (int i = 0; i < 16; ++i) {
    const int n = (tid >> 6) + i * 4;
    const int kk = tid & 63;
    const float v = tbuf[kk][n];
    const unsigned short h = rne_bf16(v);
    if (mode) {
      const size_t rowb = (size_t)(roff + n0 + n) * 512;
      dst[rowb + k0 + kk] = h;
      dst[rowb + 256 + k0 + kk] = h;
    } else {
      dst[(size_t)(n0 + n) * 256 + k0 + kk] = h;
    }
  }
}

// ---------------- bf16 MFMA GEMM, m97 structure ----------------
// MODE: 0 = f32 out; 1 = bf16 out;
// 2 = mixed (col<256 -> f32 C1 ldc 256; col>=256 -> bf16 C2 ldc 128)
template<int KSTEPS, int MODE>
__global__ __launch_bounds__(256) void gemm_mfma(
    const unsigned short* __restrict__ A, int lda,
    const unsigned short* __restrict__ Bt,   // [N][KSTEPS*64]
    const float* __restrict__ bias, const float* __restrict__ bias2,
    void* __restrict__ C1, int ldc, void* __restrict__ C2)
{
  constexpr int LDB = KSTEPS * 64;
  __shared__ unsigned short As[128 * 64];
  __shared__ unsigned short Bs[128 * 64];
  const int tid = threadIdx.x;
  const int w = tid >> 6, lane = tid & 63;
  const int wm = w >> 1, wn = w & 1;
  const int lr = lane & 15, lk = lane >> 4;
  const int m0 = blockIdx.y * 128, n0 = blockIdx.x * 128;

  f32x4 acc[4][4] = {};

  for (int t = 0; t < KSTEPS; ++t) {
    const int ka = t * 64;
#pragma unroll
    for (int i = 0; i < 4; ++i) {
      const int rbase = i * 32 + w * 8;
      const int row = rbase + (lane >> 3);
      const int slot = lane & 7;
      const int gs = slot ^ (row & 7);                 // inverse-swizzle the SOURCE (rule 21)
      const unsigned short* gp = A + (size_t)(m0 + row) * lda + ka + gs * 8;
      __builtin_amdgcn_global_load_lds(
          (const __attribute__((address_space(1))) uint_t*)gp,
          (__attribute__((address_space(3))) uint_t*)(As + rbase * 64), 16, 0, 0);
    }
#pragma unroll
    for (int i = 0; i < 4; ++i) {
      const int rbase = i * 32 + w * 8;
      const int row = rbase + (lane >> 3);
      const int slot = lane & 7;
      const int gs = slot ^ (row & 7);
      const unsigned short* gp = Bt + (size_t)(n0 + row) * LDB + ka + gs * 8;
      __builtin_amdgcn_global_load_lds(
          (const __attribute__((address_space(1))) uint_t*)gp,
          (__attribute__((address_space(3))) uint_t*)(Bs + rbase * 64), 16, 0, 0);
    }
    asm volatile("s_waitcnt vmcnt(0)" ::: "memory");
    __syncthreads();
#pragma unroll
    for (int kk = 0; kk < 2; ++kk) {
      bf16x8 af[4], bfv[4];
#pragma unroll
      for (int m = 0; m < 4; ++m) {
        const int row = wm * 64 + m * 16 + lr;
        const int so = (kk * 4 + lk) ^ (row & 7);      // swizzled read
        af[m] = *(const bf16x8*)((const char*)As + row * 128 + so * 16);
      }
#pragma unroll
      for (int n = 0; n < 4; ++n) {
        const int row = wn * 64 + n * 16 + lr;
        const int so = (kk * 4 + lk) ^ (row & 7);
        bfv[n] = *(const bf16x8*)((const char*)Bs + row * 128 + so * 16);
      }
#pragma unroll
      for (int m = 0; m < 4; ++m)
#pragma unroll
        for (int n = 0; n < 4; ++n)
          acc[m][n] = __builtin_amdgcn_mfma_f32_16x16x32_bf16(af[m], bfv[n], acc[m][n], 0, 0, 0);
    }
    __syncthreads();
  }
#pragma unroll
  for (int n = 0; n < 4; ++n) {
    const int col = n0 + wn * 64 + n * 16 + lr;
    const float bv = (MODE == 2 && col >= 256) ? bias2[col - 256] : bias[col];
#pragma unroll
    for (int m = 0; m < 4; ++m) {
      const int rbase = m0 + wm * 64 + m * 16 + lk * 4;
#pragma unroll
      for (int j = 0; j < 4; ++j) {
        const float v = acc[m][n][j] + bv;
        const int row = rbase + j;
        if (MODE == 0) {
          ((float*)C1)[(size_t)row * ldc + col] = v;
        } else if (MODE == 1) {
          ((unsigned short*)C1)[(size_t)row * ldc + col] = rne_bf16(v);
        } else {
          if (col < 256) ((float*)C1)[(size_t)row * 256 + col] = v;
          else           ((unsigned short*)C2)[(size_t)row * 128 + (col - 256)] = rne_bf16(v);
        }
      }
    }
  }
}

// ---------------- sampler v10: v6 two-phase structure, VGPR diet ----------------
// Same algorithm as v6 (two-phase, packed 16B/point LDS exchange, fully clamped
// indices). Register diet: (a) phase 1 processes offsets in two float4 halves,
// (b) epilogue uses v_cvt_pk_bf16_f32 (4+4 packs, two uint4 stores) instead of
// 16x rne_bf16. Goal: VGPR <= 64 (occupancy step, m69) WITHOUT launch-bounds
// coercion (v9's forced cap spilled: VGPR 32, +14MB scratch writes).
__global__ __launch_bounds__(256) void msda_sample_v10(
    const float* __restrict__ off_buf,            // [M,256]
    const unsigned short* __restrict__ logit_buf, // [M,128] bf16
    const unsigned short* __restrict__ value,     // [B,LV,256] bf16
    const float* __restrict__ ref_pts,            // [B,LQ,4,2]
    const int*  __restrict__ sshapes, const int* __restrict__ lstart,
    unsigned short* __restrict__ samp3)           // [M,512]
{
  __shared__ uint_t wlds[64 * 68];                // 17,408 B
  const int tid = threadIdx.x;
  const int q0 = blockIdx.x * 8;
  const int b  = blockIdx.x / (LQ / 8);
  const int q  = tid >> 5;
  const int qg = q0 + q;

  // ---------- phase 1: lane = (q, h, l) ----------
  {
    const int h  = (tid >> 2) & 7;
    const int l  = tid & 3;
    const int Hl = sshapes[2 * l], Wl = sshapes[2 * l + 1];
    const int st = lstart[l];
    const float rx = ref_pts[(size_t)qg * 8 + l * 2 + 0];
    const float ry = ref_pts[(size_t)qg * 8 + l * 2 + 1];
    const float fx = rx * (float)Wl - 0.5f;
    const float fy = ry * (float)Hl - 0.5f;

    const float* ob = off_buf + (size_t)qg * 256 + h * 32 + l * 8;

    const uint2 lgu = *(const uint2*)(logit_buf + (size_t)qg * 128 + h * 16 + l * 4);
    float lg0 = __uint_as_float(lgu.x << 16);
    float lg1 = __uint_as_float(lgu.x & 0xffff0000u);
    float lg2 = __uint_as_float(lgu.y << 16);
    float lg3 = __uint_as_float(lgu.y & 0xffff0000u);

    // cooperative softmax over the 16 logits of (q,h) (4 lanes x 4)
    float mx = fmaxf(fmaxf(lg0, lg1), fmaxf(lg2, lg3));
    mx = fmaxf(mx, __shfl_xor(mx, 1));
    mx = fmaxf(mx, __shfl_xor(mx, 2));
    float ex[4];
    ex[0] = __expf(lg0 - mx); ex[1] = __expf(lg1 - mx);
    ex[2] = __expf(lg2 - mx); ex[3] = __expf(lg3 - mx);
    float ssum = ex[0] + ex[1] + ex[2] + ex[3];
    ssum += __shfl_xor(ssum, 1);
    ssum += __shfl_xor(ssum, 2);
    const float inv = 1.f / ssum;

    const uint_t base_idx = (uint_t)b * LV + (uint_t)st;   // absolute element-row base
    uint_t* wrow = wlds + (size_t)(q * 8 + h) * 68;

#pragma unroll
    for (int pp = 0; pp < 2; ++pp) {
      const float4 o = *(const float4*)(ob + pp * 4);
      const float oxv[2] = {o.x, o.z};
      const float oyv[2] = {o.y, o.w};
#pragma unroll
      for (int ps = 0; ps < 2; ++ps) {
        const int p = pp * 2 + ps;
        const float x = fx + oxv[ps];
        const float y = fy + oyv[ps];
        const float aw = ex[p] * inv;
        const float xf = floorf(x), yf = floorf(y);
        const int x0i = (int)xf, y0i = (int)yf;
        const float wx1 = x - xf, wy1 = y - yf;
        const float wx0 = 1.f - wx1, wy0 = 1.f - wy1;
        const int x1i = x0i + 1, y1i = y0i + 1;
        const bool vx0 = (uint_t)x0i < (uint_t)Wl, vx1 = (uint_t)x1i < (uint_t)Wl;
        const bool vy0 = (uint_t)y0i < (uint_t)Hl, vy1 = (uint_t)y1i < (uint_t)Hl;
        const int xc0 = min(max(x0i, 0), Wl - 1), xc1 = min(max(x1i, 0), Wl - 1);
        const int yc0 = min(max(y0i, 0), Hl - 1), yc1 = min(max(y1i, 0), Hl - 1);
        const float awy0 = aw * wy0, awy1 = aw * wy1;
        const float w00 = (vy0 && vx0) ? awy0 * wx0 : 0.f;
        const float w01 = (vy0 && vx1) ? awy0 * wx1 : 0.f;
        const float w10 = (vy1 && vx0) ? awy1 * wx0 : 0.f;
        const float w11 = (vy1 && vx1) ? awy1 * wx1 : 0.f;
        const uint_t r0 = base_idx + (uint_t)(yc0 * Wl), r1 = base_idx + (uint_t)(yc1 * Wl);
        uint4 pk;
        pk.x = f2h2(w00, w01);
        pk.y = f2h2(w10, w11);
        pk.z = (r0 + (uint_t)xc0) | ((r0 + (uint_t)xc1) << 16);
        pk.w = (r1 + (uint_t)xc0) | ((r1 + (uint_t)xc1) << 16);
        *(uint4*)(wrow + (l * 4 + p) * 4) = pk;
      }
    }
  }
  __syncthreads();

  // ---------- phase 2: lane = (q, h, dg) ----------
  const int h  = (tid >> 2) & 7;
  const int dg = tid & 3;
  const uint_t* wrow = wlds + (size_t)(q * 8 + h) * 68;
  const char* vbyte = (const char*)value + (uint_t)h * 64u + (uint_t)dg * 16u;
  float acc[8] = {};

#define ACCUM8V(U4, WV) {                                                          \
    const uint_t uu0 = (U4).x, uu1 = (U4).y, uu2 = (U4).z, uu3 = (U4).w;           \
    acc[0] = fmaf((WV), __uint_as_float(uu0 << 16),         acc[0]);               \
    acc[1] = fmaf((WV), __uint_as_float(uu0 & 0xffff0000u), acc[1]);               \
    acc[2] = fmaf((WV), __uint_as_float(uu1 << 16),         acc[2]);               \
    acc[3] = fmaf((WV), __uint_as_float(uu1 & 0xffff0000u), acc[3]);               \
    acc[4] = fmaf((WV), __uint_as_float(uu2 << 16),         acc[4]);               \
    acc[5] = fmaf((WV), __uint_as_float(uu2 & 0xffff0000u), acc[5]);               \
    acc[6] = fmaf((WV), __uint_as_float(uu3 << 16),         acc[6]);               \
    acc[7] = fmaf((WV), __uint_as_float(uu3 & 0xffff0000u), acc[7]); }

#pragma unroll
  for (int pt = 0; pt < 16; ++pt) {
    const uint4 pk = *(const uint4*)(wrow + pt * 4);
    const float w0 = h_lo(pk.x), w1 = h_hi(pk.x);
    const float w2 = h_lo(pk.y), w3 = h_hi(pk.y);
    const uint_t i0 = pk.z & 0xffffu, i1 = pk.z >> 16;
    const uint_t i2 = pk.w & 0xffffu, i3 = pk.w >> 16;
    { const uint4 g = *(const uint4*)(vbyte + (size_t)i0 * 512u); ACCUM8V(g, w0); }
    { const uint4 g = *(const uint4*)(vbyte + (size_t)i1 * 512u); ACCUM8V(g, w1); }
    { const uint4 g = *(const uint4*)(vbyte + (size_t)i2 * 512u); ACCUM8V(g, w2); }
    { const uint4 g = *(const uint4*)(vbyte + (size_t)i3 * 512u); ACCUM8V(g, w3); }
  }

  // epilogue: packed bf16 hi|lo via v_cvt_pk_bf16_f32 (RNE), two 16B stores
  uint_t hp[4], lp[4];
#pragma unroll
  for (int i = 0; i < 4; ++i) {
    hp[i] = cvt_pk_bf16(acc[2 * i], acc[2 * i + 1]);
    const float lo0 = acc[2 * i]     - __uint_as_float(hp[i] << 16);
    const float lo1 = acc[2 * i + 1] - __uint_as_float(hp[i] & 0xffff0000u);
    lp[i] = cvt_pk_bf16(lo0, lo1);
  }
  unsigned short* op = samp3 + (size_t)qg * 512 + h * 32 + dg * 8;
  *(uint4*)(op)       = make_uint4(hp[0], hp[1], hp[2], hp[3]);
  *(uint4*)(op + 256) = make_uint4(lp[0], lp[1], lp[2], lp[3]);
}

extern "C" void kernel_launch(void* const* d_in, const int* in_sizes, int n_in,
                              void* d_out, int out_size, void* d_ws, size_t ws_size,
                              hipStream_t stream) {
  const float* query         = (const float*)d_in[0];
  const float* ref_pts       = (const float*)d_in[1];
  const float* input_flatten = (const float*)d_in[2];
  const int*   sshapes       = (const int*)d_in[3];
  const int*   lstart        = (const int*)d_in[4];
  const float* w_val  = (const float*)d_in[5];
  const float* b_val  = (const float*)d_in[6];
  const float* w_off  = (const float*)d_in[7];
  const float* b_off  = (const float*)d_in[8];
  const float* w_attn = (const float*)d_in[9];
  const float* b_attn = (const float*)d_in[10];
  const float* w_out  = (const float*)d_in[11];
  const float* b_out  = (const float*)d_in[12];
  float* out = (float*)d_out;

  char* ws = (char*)d_ws;
  unsigned short* Q3     = (unsigned short*)(ws);                 // 22,282,240 B (reused as samp3)
  unsigned short* IFh    = (unsigned short*)(ws + 22282240);      // 11,141,120
  unsigned short* valb   = (unsigned short*)(ws + 33423360);      // 11,141,120
  float*          offb   = (float*)(ws + 44564480);               // 22,282,240
  unsigned short* logitb = (unsigned short*)(ws + 66846720);      //  5,570,560
  unsigned short* Wcat   = (unsigned short*)(ws + 72417280);      //    393,216  [384][512]
  unsigned short* Wo2    = (unsigned short*)(ws + 72810496);      //    262,144  [256][512]
  unsigned short* Wvt    = (unsigned short*)(ws + 73072640);      //    131,072  [256][256]
  unsigned short* samp3  = Q3;  // Q3 dead after the fused off/logit GEMM

  dim3 blk(256);
  conv_inputs<<<dim3(M_TOT / 4), blk, 0, stream>>>(query, input_flatten, Q3, IFh);
  conv_weights<<<dim3(4, 14), blk, 0, stream>>>(w_off, w_out, w_val, w_attn, Wcat, Wo2, Wvt);
  // value = IFh @ w_val (plain bf16), out bf16
  gemm_mfma<4, 1><<<dim3(2, M_TOT / 128), blk, 0, stream>>>(
      IFh, 256, Wvt, b_val, nullptr, (void*)valb, 256, nullptr);
  // fused: [off | logits] = [Q_hi|Q_lo] @ Wcat^T, K=512, mixed epilogue
  gemm_mfma<8, 2><<<dim3(3, M_TOT / 128), blk, 0, stream>>>(
      Q3, 512, Wcat, b_off, b_attn, (void*)offb, 256, (void*)logitb);
  msda_sample_v10<<<dim3(M_TOT / 8), blk, 0, stream>>>(
      offb, logitb, valb, ref_pts, sshapes, lstart, samp3);
  // out = [samp_hi|samp_lo] @ [Wo_hi|Wo_hi], K=512, out f32
  gemm_mfma<8, 0><<<dim3(2, M_TOT / 128), blk, 0, stream>>>(
      samp3, 512, Wo2, b_out, nullptr, (void*)out, 256, nullptr);
}

// Round 11
// 105.094 us; speedup vs baseline: 1.1820x; 1.0961x over previous
//
#include <hip/hip_runtime.h>
#include <hip/hip_fp16.h>
#include <math.h>

#define N_HEADS 8
#define N_LEVELS 4
#define N_POINTS 4
#define LQ 5440
#define LV 5440
#define BATCH_ 4
#define M_TOT (BATCH_ * LQ)   // 21760

typedef __bf16 bf16x8 __attribute__((ext_vector_type(8)));
typedef float f32x4 __attribute__((ext_vector_type(4)));
typedef unsigned int uint_t;

__device__ __forceinline__ unsigned short rne_bf16(float x) {
  uint_t u = __float_as_uint(x);
  uint_t r = u + 0x7fffu + ((u >> 16) & 1u);
  return (unsigned short)(r >> 16);
}
__device__ __forceinline__ float bf16_to_f(unsigned short h) {
  return __uint_as_float(((uint_t)h) << 16);
}
__device__ __forceinline__ uint_t f2h2(float a, float b) {   // pack 2 f32 -> half2 (RNE)
  const unsigned short ua = __half_as_ushort(__float2half(a));
  const unsigned short ub = __half_as_ushort(__float2half(b));
  return (uint_t)ua | ((uint_t)ub << 16);
}
__device__ __forceinline__ float h_lo(uint_t u) {
  return __half2float(__ushort_as_half((unsigned short)(u & 0xffffu)));
}
__device__ __forceinline__ float h_hi(uint_t u) {
  return __half2float(__ushort_as_half((unsigned short)(u >> 16)));
}

// ---------------- input conversion: query -> Q3 (hi|lo), input_flatten -> IFh ----------------
__global__ __launch_bounds__(256) void conv_inputs(
    const float* __restrict__ q, const float* __restrict__ iff,
    unsigned short* __restrict__ Q3, unsigned short* __restrict__ IFh)
{
  const int t = blockIdx.x * 256 + threadIdx.x;   // 0 .. M*64
  const int r = t >> 6;
  const int c = (t & 63) * 4;
  const float4 qa = *(const float4*)(q + (size_t)r * 256 + c);
  ushort4 h, l;
  {
    const float v[4] = {qa.x, qa.y, qa.z, qa.w};
    unsigned short hh[4], ll[4];
#pragma unroll
    for (int i = 0; i < 4; ++i) {
      hh[i] = rne_bf16(v[i]);
      ll[i] = rne_bf16(v[i] - bf16_to_f(hh[i]));
    }
    h = make_ushort4(hh[0], hh[1], hh[2], hh[3]);
    l = make_ushort4(ll[0], ll[1], ll[2], ll[3]);
  }
  *(ushort4*)(Q3 + (size_t)r * 512 + c) = h;
  *(ushort4*)(Q3 + (size_t)r * 512 + 256 + c) = l;
  const float4 fa = *(const float4*)(iff + (size_t)r * 256 + c);
  *(ushort4*)(IFh + (size_t)r * 256 + c) =
      make_ushort4(rne_bf16(fa.x), rne_bf16(fa.y), rne_bf16(fa.z), rne_bf16(fa.w));
}

// ---------------- weight conversion (transpose + bf16) ----------------
// mode 1 (2-term split): W[n][0..255]=hi, [256..511]=hi  (pairs with A=[hi|lo])
// mode 0: Wt[n][0..255]=hi
// Wcat: rows 0..255 = w_off, rows 256..383 = w_attn (both mode 1)
__global__ __launch_bounds__(256) void conv_weights(
    const float* __restrict__ w_off, const float* __restrict__ w_out,
    const float* __restrict__ w_val, const float* __restrict__ w_attn,
    unsigned short* __restrict__ Wcat, unsigned short* __restrict__ Wo2,
    unsigned short* __restrict__ Wvt)
{
  __shared__ float tbuf[64][65];
  const int tid = threadIdx.x;
  const int k0 = blockIdx.x * 64;
  const int yy = blockIdx.y;
  const float* src; unsigned short* dst; int N; int mode; int ntile; int roff = 0;
  if (yy < 4)       { src = w_off;  dst = Wcat; N = 256; mode = 1; ntile = yy; }
  else if (yy < 8)  { src = w_out;  dst = Wo2;  N = 256; mode = 1; ntile = yy - 4; }
  else if (yy < 12) { src = w_val;  dst = Wvt;  N = 256; mode = 0; ntile = yy - 8; }
  else              { src = w_attn; dst = Wcat; N = 128; mode = 1; ntile = yy - 12; roff = 256; }
  const int n0 = ntile * 64;
#pragma unroll
  for (int i = 0; i < 16; ++i) {
    const int r = (tid >> 6) + i * 4;
    const int c = tid & 63;
    tbuf[r][c] = src[(size_t)(k0 + r) * N + n0 + c];
  }
  __syncthreads();
#pragma unroll
  for (int i = 0; i < 16; ++i) {
    const int n = (tid >> 6) + i * 4;
    const int kk = tid & 63;
    const float v = tbuf[kk][n];
    const unsigned short h = rne_bf16(v);
    if (mode) {
      const size_t rowb = (size_t)(roff + n0 + n) * 512;
      dst[rowb + k0 + kk] = h;
      dst[rowb + 256 + k0 + kk] = h;
    } else {
      dst[(size_t)(n0 + n) * 256 + k0 + kk] = h;
    }
  }
}

// ---------------- bf16 MFMA GEMM, m97 structure ----------------
// MODE: 0 = f32 out; 1 = bf16 out;
// 2 = mixed (col<256 -> f16 C1 ldc 256; col>=256 -> bf16 C2 ldc 128)
template<int KSTEPS, int MODE>
__global__ __launch_bounds__(256) void gemm_mfma(
    const unsigned short* __restrict__ A, int lda,
    const unsigned short* __restrict__ Bt,   // [N][KSTEPS*64]
    const float* __restrict__ bias, const float* __restrict__ bias2,
    void* __restrict__ C1, int ldc, void* __restrict__ C2)
{
  constexpr int LDB = KSTEPS * 64;
  __shared__ unsigned short As[128 * 64];
  __shared__ unsigned short Bs[128 * 64];
  const int tid = threadIdx.x;
  const int w = tid >> 6, lane = tid & 63;
  const int wm = w >> 1, wn = w & 1;
  const int lr = lane & 15, lk = lane >> 4;
  const int m0 = blockIdx.y * 128, n0 = blockIdx.x * 128;

  f32x4 acc[4][4] = {};

  for (int t = 0; t < KSTEPS; ++t) {
    const int ka = t * 64;
#pragma unroll
    for (int i = 0; i < 4; ++i) {
      const int rbase = i * 32 + w * 8;
      const int row = rbase + (lane >> 3);
      const int slot = lane & 7;
      const int gs = slot ^ (row & 7);                 // inverse-swizzle the SOURCE (rule 21)
      const unsigned short* gp = A + (size_t)(m0 + row) * lda + ka + gs * 8;
      __builtin_amdgcn_global_load_lds(
          (const __attribute__((address_space(1))) uint_t*)gp,
          (__attribute__((address_space(3))) uint_t*)(As + rbase * 64), 16, 0, 0);
    }
#pragma unroll
    for (int i = 0; i < 4; ++i) {
      const int rbase = i * 32 + w * 8;
      const int row = rbase + (lane >> 3);
      const int slot = lane & 7;
      const int gs = slot ^ (row & 7);
      const unsigned short* gp = Bt + (size_t)(n0 + row) * LDB + ka + gs * 8;
      __builtin_amdgcn_global_load_lds(
          (const __attribute__((address_space(1))) uint_t*)gp,
          (__attribute__((address_space(3))) uint_t*)(Bs + rbase * 64), 16, 0, 0);
    }
    asm volatile("s_waitcnt vmcnt(0)" ::: "memory");
    __syncthreads();
#pragma unroll
    for (int kk = 0; kk < 2; ++kk) {
      bf16x8 af[4], bfv[4];
#pragma unroll
      for (int m = 0; m < 4; ++m) {
        const int row = wm * 64 + m * 16 + lr;
        const int so = (kk * 4 + lk) ^ (row & 7);      // swizzled read
        af[m] = *(const bf16x8*)((const char*)As + row * 128 + so * 16);
      }
#pragma unroll
      for (int n = 0; n < 4; ++n) {
        const int row = wn * 64 + n * 16 + lr;
        const int so = (kk * 4 + lk) ^ (row & 7);
        bfv[n] = *(const bf16x8*)((const char*)Bs + row * 128 + so * 16);
      }
#pragma unroll
      for (int m = 0; m < 4; ++m)
#pragma unroll
        for (int n = 0; n < 4; ++n)
          acc[m][n] = __builtin_amdgcn_mfma_f32_16x16x32_bf16(af[m], bfv[n], acc[m][n], 0, 0, 0);
    }
    __syncthreads();
  }
#pragma unroll
  for (int n = 0; n < 4; ++n) {
    const int col = n0 + wn * 64 + n * 16 + lr;
    const float bv = (MODE == 2 && col >= 256) ? bias2[col - 256] : bias[col];
#pragma unroll
    for (int m = 0; m < 4; ++m) {
      const int rbase = m0 + wm * 64 + m * 16 + lk * 4;
#pragma unroll
      for (int j = 0; j < 4; ++j) {
        const float v = acc[m][n][j] + bv;
        const int row = rbase + j;
        if (MODE == 0) {
          ((float*)C1)[(size_t)row * ldc + col] = v;
        } else if (MODE == 1) {
          ((unsigned short*)C1)[(size_t)row * ldc + col] = rne_bf16(v);
        } else {
          if (col < 256) ((unsigned short*)C1)[(size_t)row * 256 + col] =
              __half_as_ushort(__float2half(v));                 // offsets as f16
          else           ((unsigned short*)C2)[(size_t)row * 128 + (col - 256)] = rne_bf16(v);
        }
      }
    }
  }
}

// ---------------- sampler v11: v6 two-phase + batch->XCD swizzle + f16 offsets ----------------
// Block swizzle: physical dispatch index P presumed round-robin over 8 XCDs (P%8).
// Remap so XCD pair {2b,2b+1} handles exactly batch b: per-XCD value working set
// drops 11.1MB -> 2.79MB (< 4MB L2/XCD), making the 713MB gather stream L2-resident.
// L = ((P&7)>>1)*680 + (P&1)*340 + (P>>3), bijective for P in [0,2720).
__global__ __launch_bounds__(256) void msda_sample_v11(
    const unsigned short* __restrict__ off_buf,   // [M,256] f16
    const unsigned short* __restrict__ logit_buf, // [M,128] bf16
    const unsigned short* __restrict__ value,     // [B,LV,256] bf16
    const float* __restrict__ ref_pts,            // [B,LQ,4,2]
    const int*  __restrict__ sshapes, const int* __restrict__ lstart,
    unsigned short* __restrict__ samp3)           // [M,512]
{
  __shared__ uint_t wlds[64 * 68];                // 17,408 B
  const int tid = threadIdx.x;
  const int P  = blockIdx.x;
  const int L  = (((P & 7) >> 1) * 680) + ((P & 1) * 340) + (P >> 3);
  const int q0 = L * 8;
  const int b  = L / (LQ / 8);
  const int q  = tid >> 5;
  const int qg = q0 + q;

  // ---------- phase 1: lane = (q, h, l) ----------
  {
    const int h  = (tid >> 2) & 7;
    const int l  = tid & 3;
    const int Hl = sshapes[2 * l], Wl = sshapes[2 * l + 1];
    const int st = lstart[l];
    const float rx = ref_pts[(size_t)qg * 8 + l * 2 + 0];
    const float ry = ref_pts[(size_t)qg * 8 + l * 2 + 1];
    const float fx = rx * (float)Wl - 0.5f;
    const float fy = ry * (float)Hl - 0.5f;

    // 8 f16 offsets for this (h,l): one uint4, coalesced
    const uint4 og = *(const uint4*)(off_buf + (size_t)qg * 256 + h * 32 + l * 8);
    const float offv[8] = {h_lo(og.x), h_hi(og.x), h_lo(og.y), h_hi(og.y),
                           h_lo(og.z), h_hi(og.z), h_lo(og.w), h_hi(og.w)};

    const uint2 lgu = *(const uint2*)(logit_buf + (size_t)qg * 128 + h * 16 + l * 4);
    float lg[4];
    lg[0] = __uint_as_float(lgu.x << 16);
    lg[1] = __uint_as_float(lgu.x & 0xffff0000u);
    lg[2] = __uint_as_float(lgu.y << 16);
    lg[3] = __uint_as_float(lgu.y & 0xffff0000u);

    // cooperative softmax over the 16 logits of (q,h) (4 lanes x 4)
    float mx = fmaxf(fmaxf(lg[0], lg[1]), fmaxf(lg[2], lg[3]));
    mx = fmaxf(mx, __shfl_xor(mx, 1));
    mx = fmaxf(mx, __shfl_xor(mx, 2));
    float ex[4]; float ssum = 0.f;
#pragma unroll
    for (int p = 0; p < 4; ++p) { ex[p] = __expf(lg[p] - mx); ssum += ex[p]; }
    ssum += __shfl_xor(ssum, 1);
    ssum += __shfl_xor(ssum, 2);
    const float inv = 1.f / ssum;

    const uint_t base_idx = (uint_t)b * LV + (uint_t)st;   // absolute element-row base
    uint_t* wrow = wlds + (size_t)(q * 8 + h) * 68;

#pragma unroll
    for (int p = 0; p < 4; ++p) {
      const float x = fx + offv[p * 2 + 0];
      const float y = fy + offv[p * 2 + 1];
      const float aw = ex[p] * inv;
      const float xf = floorf(x), yf = floorf(y);
      const int x0i = (int)xf, y0i = (int)yf;
      const float wx1 = x - xf, wy1 = y - yf;
      const float wx0 = 1.f - wx1, wy0 = 1.f - wy1;
      const int x1i = x0i + 1, y1i = y0i + 1;
      const bool vx0 = (uint_t)x0i < (uint_t)Wl, vx1 = (uint_t)x1i < (uint_t)Wl;
      const bool vy0 = (uint_t)y0i < (uint_t)Hl, vy1 = (uint_t)y1i < (uint_t)Hl;
      const int xc0 = min(max(x0i, 0), Wl - 1), xc1 = min(max(x1i, 0), Wl - 1);
      const int yc0 = min(max(y0i, 0), Hl - 1), yc1 = min(max(y1i, 0), Hl - 1);
      const float awy0 = aw * wy0, awy1 = aw * wy1;
      const float w00 = (vy0 && vx0) ? awy0 * wx0 : 0.f;
      const float w01 = (vy0 && vx1) ? awy0 * wx1 : 0.f;
      const float w10 = (vy1 && vx0) ? awy1 * wx0 : 0.f;
      const float w11 = (vy1 && vx1) ? awy1 * wx1 : 0.f;
      const uint_t r0 = base_idx + (uint_t)(yc0 * Wl), r1 = base_idx + (uint_t)(yc1 * Wl);
      uint4 pk;
      pk.x = f2h2(w00, w01);
      pk.y = f2h2(w10, w11);
      pk.z = (r0 + (uint_t)xc0) | ((r0 + (uint_t)xc1) << 16);
      pk.w = (r1 + (uint_t)xc0) | ((r1 + (uint_t)xc1) << 16);
      *(uint4*)(wrow + (l * 4 + p) * 4) = pk;
    }
  }
  __syncthreads();

  // ---------- phase 2: lane = (q, h, dg) ----------
  const int h  = (tid >> 2) & 7;
  const int dg = tid & 3;
  const uint_t* wrow = wlds + (size_t)(q * 8 + h) * 68;
  const char* vbyte = (const char*)value + (uint_t)h * 64u + (uint_t)dg * 16u;
  float acc[8] = {};

#define ACCUM8V(U4, WV) {                                                          \
    const uint_t uu0 = (U4).x, uu1 = (U4).y, uu2 = (U4).z, uu3 = (U4).w;           \
    acc[0] = fmaf((WV), __uint_as_float(uu0 << 16),         acc[0]);               \
    acc[1] = fmaf((WV), __uint_as_float(uu0 & 0xffff0000u), acc[1]);               \
    acc[2] = fmaf((WV), __uint_as_float(uu1 << 16),         acc[2]);               \
    acc[3] = fmaf((WV), __uint_as_float(uu1 & 0xffff0000u), acc[3]);               \
    acc[4] = fmaf((WV), __uint_as_float(uu2 << 16),         acc[4]);               \
    acc[5] = fmaf((WV), __uint_as_float(uu2 & 0xffff0000u), acc[5]);               \
    acc[6] = fmaf((WV), __uint_as_float(uu3 << 16),         acc[6]);               \
    acc[7] = fmaf((WV), __uint_as_float(uu3 & 0xffff0000u), acc[7]); }

#pragma unroll
  for (int pt = 0; pt < 16; ++pt) {
    const uint4 pk = *(const uint4*)(wrow + pt * 4);
    const float w0 = h_lo(pk.x), w1 = h_hi(pk.x);
    const float w2 = h_lo(pk.y), w3 = h_hi(pk.y);
    const uint_t i0 = pk.z & 0xffffu, i1 = pk.z >> 16;
    const uint_t i2 = pk.w & 0xffffu, i3 = pk.w >> 16;
    { const uint4 g = *(const uint4*)(vbyte + (size_t)i0 * 512u); ACCUM8V(g, w0); }
    { const uint4 g = *(const uint4*)(vbyte + (size_t)i1 * 512u); ACCUM8V(g, w1); }
    { const uint4 g = *(const uint4*)(vbyte + (size_t)i2 * 512u); ACCUM8V(g, w2); }
    { const uint4 g = *(const uint4*)(vbyte + (size_t)i3 * 512u); ACCUM8V(g, w3); }
  }

  unsigned short h8[8], l8[8];
#pragma unroll
  for (int i = 0; i < 8; ++i) {
    h8[i] = rne_bf16(acc[i]);
    l8[i] = rne_bf16(acc[i] - bf16_to_f(h8[i]));
  }
  unsigned short* op = samp3 + (size_t)qg * 512 + h * 32 + dg * 8;
  *(ushort4*)(op)       = make_ushort4(h8[0], h8[1], h8[2], h8[3]);
  *(ushort4*)(op + 4)   = make_ushort4(h8[4], h8[5], h8[6], h8[7]);
  *(ushort4*)(op + 256) = make_ushort4(l8[0], l8[1], l8[2], l8[3]);
  *(ushort4*)(op + 260) = make_ushort4(l8[4], l8[5], l8[6], l8[7]);
}

extern "C" void kernel_launch(void* const* d_in, const int* in_sizes, int n_in,
                              void* d_out, int out_size, void* d_ws, size_t ws_size,
                              hipStream_t stream) {
  const float* query         = (const float*)d_in[0];
  const float* ref_pts       = (const float*)d_in[1];
  const float* input_flatten = (const float*)d_in[2];
  const int*   sshapes       = (const int*)d_in[3];
  const int*   lstart        = (const int*)d_in[4];
  const float* w_val  = (const float*)d_in[5];
  const float* b_val  = (const float*)d_in[6];
  const float* w_off  = (const float*)d_in[7];
  const float* b_off  = (const float*)d_in[8];
  const float* w_attn = (const float*)d_in[9];
  const float* b_attn = (const float*)d_in[10];
  const float* w_out  = (const float*)d_in[11];
  const float* b_out  = (const float*)d_in[12];
  float* out = (float*)d_out;

  char* ws = (char*)d_ws;
  unsigned short* Q3     = (unsigned short*)(ws);                 // 22,282,240 B (reused as samp3)
  unsigned short* IFh    = (unsigned short*)(ws + 22282240);      // 11,141,120
  unsigned short* valb   = (unsigned short*)(ws + 33423360);      // 11,141,120
  unsigned short* offb   = (unsigned short*)(ws + 44564480);      // 11,141,120  [M,256] f16
  unsigned short* logitb = (unsigned short*)(ws + 55705600);      //  5,570,560
  unsigned short* Wcat   = (unsigned short*)(ws + 61276160);      //    393,216  [384][512]
  unsigned short* Wo2    = (unsigned short*)(ws + 61669376);      //    262,144  [256][512]
  unsigned short* Wvt    = (unsigned short*)(ws + 61931520);      //    131,072  [256][256]
  unsigned short* samp3  = Q3;  // Q3 dead after the fused off/logit GEMM

  dim3 blk(256);
  conv_inputs<<<dim3(M_TOT / 4), blk, 0, stream>>>(query, input_flatten, Q3, IFh);
  conv_weights<<<dim3(4, 14), blk, 0, stream>>>(w_off, w_out, w_val, w_attn, Wcat, Wo2, Wvt);
  // value = IFh @ w_val (plain bf16), out bf16
  gemm_mfma<4, 1><<<dim3(2, M_TOT / 128), blk, 0, stream>>>(
      IFh, 256, Wvt, b_val, nullptr, (void*)valb, 256, nullptr);
  // fused: [off | logits] = [Q_hi|Q_lo] @ Wcat^T, K=512, mixed epilogue (off as f16)
  gemm_mfma<8, 2><<<dim3(3, M_TOT / 128), blk, 0, stream>>>(
      Q3, 512, Wcat, b_off, b_attn, (void*)offb, 256, (void*)logitb);
  msda_sample_v11<<<dim3(M_TOT / 8), blk, 0, stream>>>(
      offb, logitb, valb, ref_pts, sshapes, lstart, samp3);
  // out = [samp_hi|samp_lo] @ [Wo_hi|Wo_hi], K=512, out f32
  gemm_mfma<8, 0><<<dim3(2, M_TOT / 128), blk, 0, stream>>>(
      samp3, 512, Wo2, b_out, nullptr, (void*)out, 256, nullptr);
}